// Round 6
// baseline (368.351 us; speedup 1.0000x reference)
//
#include <hip/hip_runtime.h>
#include <math.h>

typedef long long i64;

// ---------------- CSR build ----------------

__global__ void k_init(int* __restrict__ deg, int* __restrict__ fill, int N) {
    int i = blockIdx.x * blockDim.x + threadIdx.x;
    if (i < N) { deg[i] = 1; fill[i] = 0; }   // deg starts at 1 (self-loop)
}

__global__ void k_count(const int* __restrict__ ei, int E, int* __restrict__ deg, int N) {
    int e = blockIdx.x * blockDim.x + threadIdx.x;
    if (e < E) {
        int d = __builtin_nontemporal_load(ei + E + e);   // dst row (streaming)
        if (d >= 0 && d < N) atomicAdd(&deg[d], 1);
    }
}

// per-1024-tile sums of (deg-1) + dinv computation
__global__ void k_blocksum(const int* __restrict__ deg, float* __restrict__ dinv,
                           int* __restrict__ bsum, int N) {
    __shared__ int sdata[256];
    int t = threadIdx.x, b = blockIdx.x;
    int base = b * 1024 + t * 4;
    int s = 0;
    #pragma unroll
    for (int i = 0; i < 4; i++) {
        int idx = base + i;
        if (idx < N) {
            int d = deg[idx];
            s += d - 1;
            dinv[idx] = rsqrtf((float)d);
        }
    }
    sdata[t] = s; __syncthreads();
    for (int off = 128; off > 0; off >>= 1) {
        if (t < off) sdata[t] += sdata[t + off];
        __syncthreads();
    }
    if (t == 0) bsum[b] = sdata[0];
}

// exclusive scan of block sums (nb <= 256)
__global__ void k_scan_blocks(const int* __restrict__ bsum, int* __restrict__ boff, int nb) {
    __shared__ int sdata[256];
    int t = threadIdx.x;
    int v = (t < nb) ? bsum[t] : 0;
    sdata[t] = v; __syncthreads();
    for (int off = 1; off < 256; off <<= 1) {
        int u = (t >= off) ? sdata[t - off] : 0;
        __syncthreads();
        sdata[t] += u;
        __syncthreads();
    }
    if (t < nb) boff[t] = sdata[t] - v;   // exclusive
}

__global__ void k_scan_write(const int* __restrict__ deg, const int* __restrict__ boff,
                             int* __restrict__ rowptr, int N, int Etot) {
    __shared__ int sdata[256];
    int t = threadIdx.x, b = blockIdx.x;
    int base = b * 1024 + t * 4;
    int c[4]; int tsum = 0;
    #pragma unroll
    for (int i = 0; i < 4; i++) {
        int idx = base + i;
        c[i] = (idx < N) ? deg[idx] - 1 : 0;
        tsum += c[i];
    }
    sdata[t] = tsum; __syncthreads();
    for (int off = 1; off < 256; off <<= 1) {
        int u = (t >= off) ? sdata[t - off] : 0;
        __syncthreads();
        sdata[t] += u;
        __syncthreads();
    }
    int excl = sdata[t] - tsum + boff[b];
    #pragma unroll
    for (int i = 0; i < 4; i++) {
        int idx = base + i;
        if (idx < N) rowptr[idx] = excl;
        excl += c[i];
    }
    if (b == 0 && t == 0) rowptr[N] = Etot;
}

// dst-range-partitioned CSR fill: block (chunk = bid>>3, range = bid&7).
// Same-range blocks land on the same XCD (round-robin dispatch) so each
// range's 800KB col window stays in that XCD's 4MB L2. Edge reads are
// non-temporal so streaming doesn't evict the col window (R4: streaming
// evictions caused 11x write amplification).
#define FILL_CHUNK 4096
__global__ __launch_bounds__(256) void k_fill2(
    const int* __restrict__ ei, int E, int N, const int* __restrict__ rowptr,
    int* __restrict__ fill, int* __restrict__ col) {
    int range = blockIdx.x & 7;
    int chunk = blockIdx.x >> 3;
    int base  = chunk * FILL_CHUNK;
    int end   = min(base + FILL_CHUNK, E);
    int lo = (int)(((i64)N * range) >> 3);
    int hi = (int)(((i64)N * (range + 1)) >> 3);
    const int* __restrict__ dstp = ei + E;
    for (int i = base + threadIdx.x; i < end; i += 256) {
        int d = __builtin_nontemporal_load(dstp + i);
        if (d >= lo && d < hi) {
            int s = __builtin_nontemporal_load(ei + i);
            if ((unsigned)s < (unsigned)N) {
                int slot = atomicAdd(&fill[d], 1);
                col[rowptr[d] + slot] = s;
            }
        }
    }
}

// ---------------- GEMM: out[r][c] = dinv[r] * sum_k X[r][k] * W[k][c] ----------------
// Thread tile 4 rows x 4 cols; W and X staged in LDS (X padded +4 floats/row).

template<int D, int F, int THREADS, int RPB>
__global__ __launch_bounds__(THREADS) void k_gemm(
    const float* __restrict__ X, const float* __restrict__ W,
    const float* __restrict__ dinv, float* __restrict__ out, int N) {
    constexpr int CG = F / 4;           // col groups
    constexpr int XLD = D + 4;          // padded row stride
    __shared__ float Ws[D * F];
    __shared__ float Xs[RPB * XLD];
    int tid = threadIdx.x;
    int row0 = blockIdx.x * RPB;

    for (int i = tid; i < D * F / 4; i += THREADS)
        ((float4*)Ws)[i] = ((const float4*)W)[i];
    for (int i = tid; i < RPB * D / 4; i += THREADS) {
        int r = i / (D / 4), kk = i % (D / 4);
        int grow = row0 + r;
        float4 v = make_float4(0.f, 0.f, 0.f, 0.f);
        if (grow < N) v = *(const float4*)&X[(size_t)grow * D + kk * 4];
        *(float4*)&Xs[r * XLD + kk * 4] = v;
    }
    __syncthreads();

    int cg = tid % CG, rg = tid / CG;
    float acc[4][4] = {};
    const float* xb = &Xs[(rg * 4) * XLD];
    #pragma unroll 4
    for (int k = 0; k < D; ++k) {
        float4 w = *(float4*)&Ws[k * F + cg * 4];
        float x0 = xb[0 * XLD + k];
        float x1 = xb[1 * XLD + k];
        float x2 = xb[2 * XLD + k];
        float x3 = xb[3 * XLD + k];
        acc[0][0] += x0 * w.x; acc[0][1] += x0 * w.y; acc[0][2] += x0 * w.z; acc[0][3] += x0 * w.w;
        acc[1][0] += x1 * w.x; acc[1][1] += x1 * w.y; acc[1][2] += x1 * w.z; acc[1][3] += x1 * w.w;
        acc[2][0] += x2 * w.x; acc[2][1] += x2 * w.y; acc[2][2] += x2 * w.z; acc[2][3] += x2 * w.w;
        acc[3][0] += x3 * w.x; acc[3][1] += x3 * w.y; acc[3][2] += x3 * w.z; acc[3][3] += x3 * w.w;
    }
    #pragma unroll
    for (int i = 0; i < 4; i++) {
        int grow = row0 + rg * 4 + i;
        if (grow < N) {
            float dv = dinv[grow];
            float4 o = make_float4(acc[i][0] * dv, acc[i][1] * dv, acc[i][2] * dv, acc[i][3] * dv);
            *(float4*)&out[(size_t)grow * F + cg * 4] = o;
        }
    }
}

// ---------------- Aggregation: wave per node, lane = feature ----------------

__global__ __launch_bounds__(256) void k_agg1(
    const float* __restrict__ g1, const int* __restrict__ rowptr,
    const int* __restrict__ col, const float* __restrict__ dinv,
    const float* __restrict__ b1, float* __restrict__ out1, int N) {
    int wid = (int)((blockIdx.x * blockDim.x + threadIdx.x) >> 6);
    int lane = threadIdx.x & 63;
    if (wid >= N) return;
    int r0 = rowptr[wid], r1 = rowptr[wid + 1];
    float sum = g1[(size_t)wid * 64 + lane];   // self-loop term (g1 already has dinv[src])
    int e = r0;
    for (; e + 4 <= r1; e += 4) {
        int c0 = col[e], c1 = col[e + 1], c2 = col[e + 2], c3 = col[e + 3];
        float v0 = g1[(size_t)c0 * 64 + lane];
        float v1 = g1[(size_t)c1 * 64 + lane];
        float v2 = g1[(size_t)c2 * 64 + lane];
        float v3 = g1[(size_t)c3 * 64 + lane];
        sum += v0 + v1 + v2 + v3;
    }
    for (; e < r1; ++e) sum += g1[(size_t)col[e] * 64 + lane];
    out1[(size_t)wid * 64 + lane] = fmaxf(dinv[wid] * sum + b1[lane], 0.f);
}

__global__ __launch_bounds__(256) void k_agg2(
    const float* __restrict__ g2, const int* __restrict__ rowptr,
    const int* __restrict__ col, const float* __restrict__ dinv,
    const float* __restrict__ b2, float* __restrict__ out, int N) {
    int wid = (int)((blockIdx.x * blockDim.x + threadIdx.x) >> 6);
    int lane = threadIdx.x & 63;
    if (wid >= N) return;
    int cl = lane < 40 ? lane : 39;            // lanes >= 40 duplicate lane 39 (masked later)
    int r0 = rowptr[wid], r1 = rowptr[wid + 1];
    float sum = g2[(size_t)wid * 40 + cl];     // self-loop
    int e = r0;
    for (; e + 4 <= r1; e += 4) {
        int c0 = col[e], c1 = col[e + 1], c2 = col[e + 2], c3 = col[e + 3];
        float v0 = g2[(size_t)c0 * 40 + cl];
        float v1 = g2[(size_t)c1 * 40 + cl];
        float v2 = g2[(size_t)c2 * 40 + cl];
        float v3 = g2[(size_t)c3 * 40 + cl];
        sum += v0 + v1 + v2 + v3;
    }
    for (; e < r1; ++e) sum += g2[(size_t)col[e] * 40 + cl];
    float o = dinv[wid] * sum + b2[cl];
    // log-softmax over 40 classes (lanes >= 40 masked out of the reductions)
    float m = (lane < 40) ? o : -INFINITY;
    #pragma unroll
    for (int off = 32; off > 0; off >>= 1) m = fmaxf(m, __shfl_xor(m, off, 64));
    float p = (lane < 40) ? __expf(o - m) : 0.f;
    #pragma unroll
    for (int off = 32; off > 0; off >>= 1) p += __shfl_xor(p, off, 64);
    float l = __logf(p);
    if (lane < 40) out[(size_t)wid * 40 + lane] = o - m - l;
}

// ---------------- launch ----------------

extern "C" void kernel_launch(void* const* d_in, const int* in_sizes, int n_in,
                              void* d_out, int out_size, void* d_ws, size_t ws_size,
                              hipStream_t stream) {
    const float* x  = (const float*)d_in[0];
    const int*   ei = (const int*)d_in[1];      // [2, E] int32 (harness: integer -> int*)
    const float* W1 = (const float*)d_in[2];
    const float* b1 = (const float*)d_in[3];
    const float* W2 = (const float*)d_in[4];
    const float* b2 = (const float*)d_in[5];
    float* out = (float*)d_out;

    const int N = in_sizes[0] / 128;
    const int E = in_sizes[1] / 2;

    char* w = (char*)d_ws;
    size_t off = 0;
    auto alloc = [&](size_t bytes) -> char* {
        char* p = w + off;
        off += (bytes + 255) & ~(size_t)255;
        return p;
    };
    int*   deg    = (int*)alloc((size_t)N * 4);
    int*   fill   = (int*)alloc((size_t)N * 4);
    int*   rowptr = (int*)alloc((size_t)(N + 1) * 4);
    float* dinv   = (float*)alloc((size_t)N * 4);
    int*   bsum   = (int*)alloc(1024);
    int*   boff   = (int*)alloc(1024);
    int*   col    = (int*)alloc((size_t)E * 4);
    float* g1     = (float*)alloc((size_t)N * 64 * 4);
    float* out1   = (float*)alloc((size_t)N * 64 * 4);
    float* g2     = g1;  // g1 dead after agg1; reuse for layer-2 pre-agg

    int nb = (N + 1023) / 1024;

    k_init<<<(N + 255) / 256, 256, 0, stream>>>(deg, fill, N);
    k_count<<<(E + 255) / 256, 256, 0, stream>>>(ei, E, deg, N);
    k_blocksum<<<nb, 256, 0, stream>>>(deg, dinv, bsum, N);
    k_scan_blocks<<<1, 256, 0, stream>>>(bsum, boff, nb);
    k_scan_write<<<nb, 256, 0, stream>>>(deg, boff, rowptr, N, E);

    int nchunks = (E + FILL_CHUNK - 1) / FILL_CHUNK;
    k_fill2<<<nchunks * 8, 256, 0, stream>>>(ei, E, N, rowptr, fill, col);

    // layer 1: g1 = dinv * (x @ W1); agg + relu -> out1
    k_gemm<128, 64, 256, 64><<<(N + 63) / 64, 256, 0, stream>>>(x, W1, dinv, g1, N);
    k_agg1<<<(N + 3) / 4, 256, 0, stream>>>(g1, rowptr, col, dinv, b1, out1, N);

    // layer 2: g2 = dinv * (out1 @ W2); agg + bias + log_softmax -> out
    k_gemm<64, 40, 320, 128><<<(N + 127) / 128, 320, 0, stream>>>(out1, W2, dinv, g2, N);
    k_agg2<<<(N + 3) / 4, 256, 0, stream>>>(g2, rowptr, col, dinv, b2, out, N);
}

// Round 7
// 253.958 us; speedup vs baseline: 1.4504x; 1.4504x over previous
//
#include <hip/hip_runtime.h>
#include <math.h>

typedef long long i64;

// ================= CSR build: 2-phase radix partition by dst =================
// NPB=512 nodes per bucket; B=ceil(N/512)=196 buckets. Every global access is
// streaming-coalesced or bucket-contiguous; col written exactly once (R6: cache
// -residency-based locality failed, 10x write amp on scattered 4B col writes).

#define NPB_SHIFT 9
#define NPB 512
#define LCAP 16384     // max edges per bucket staged in LDS (mean 8192, sigma~90)
#define P1C 4096       // edges per p1place chunk

__global__ void k_zeroB(int* __restrict__ bcnt, int B) {
    int t = threadIdx.x;
    if (t <= B) bcnt[t] = 0;
}

__global__ __launch_bounds__(256) void k_p1count(
    const int* __restrict__ dst, int E, int B, int* __restrict__ bcnt) {
    __shared__ int lb[256];
    int t = threadIdx.x;
    lb[t] = 0; __syncthreads();
    int cpb = (E + gridDim.x - 1) / gridDim.x;
    int s0 = blockIdx.x * cpb, s1 = min(E, s0 + cpb);
    for (int i = s0 + t; i < s1; i += 256)
        atomicAdd(&lb[dst[i] >> NPB_SHIFT], 1);
    __syncthreads();
    if (t < B && lb[t]) atomicAdd(&bcnt[t], lb[t]);
}

// 1 block: exclusive scan of 196 bucket counts -> bstart; init cursors
__global__ void k_scanB(const int* __restrict__ bcnt, int B, int E,
                        int* __restrict__ bstart, int* __restrict__ cursor) {
    __shared__ int s[256];
    int t = threadIdx.x;
    int v = (t < B) ? bcnt[t] : 0;
    s[t] = v; __syncthreads();
    for (int off = 1; off < 256; off <<= 1) {
        int u = (t >= off) ? s[t - off] : 0;
        __syncthreads();
        s[t] += u;
        __syncthreads();
    }
    int excl = s[t] - v;
    if (t < B) { bstart[t] = excl; cursor[t] = excl; }
    if (t == 0) bstart[B] = E;
}

// stage chunk in LDS; one global atomicAdd per (chunk,bucket); write pairs in
// bucket-contiguous runs (~21 pairs = 168B per run)
__global__ __launch_bounds__(256) void k_p1place(
    const int* __restrict__ src, const int* __restrict__ dst, int E, int B,
    int* __restrict__ cursor, uint2* __restrict__ pairs) {
    __shared__ int ls_s[P1C];
    __shared__ int ls_d[P1C];
    __shared__ int lb[256];
    __shared__ int lbase[256];
    int t = threadIdx.x;
    int s0 = blockIdx.x * P1C, s1 = min(E, s0 + P1C), n = s1 - s0;
    lb[t] = 0; __syncthreads();
    for (int i = t; i < n; i += 256) {
        int d = dst[s0 + i];
        ls_d[i] = d;
        ls_s[i] = src[s0 + i];
        atomicAdd(&lb[d >> NPB_SHIFT], 1);
    }
    __syncthreads();
    if (t < B && lb[t]) lbase[t] = atomicAdd(&cursor[t], lb[t]);
    __syncthreads();
    lb[t] = 0; __syncthreads();
    for (int i = t; i < n; i += 256) {
        int d = ls_d[i];
        int bkt = d >> NPB_SHIFT;
        int slot = atomicAdd(&lb[bkt], 1);
        pairs[lbase[bkt] + slot] = make_uint2((unsigned)ls_s[i], (unsigned)d);
    }
}

// block = bucket: per-node degree count (LDS atomics), 512-wide scan ->
// rowptr + dinv; place col in LDS image; write col coalesced exactly once.
__global__ __launch_bounds__(512) void k_p2(
    const uint2* __restrict__ pairs, const int* __restrict__ bstart,
    int* __restrict__ rowptr, float* __restrict__ dinv,
    int* __restrict__ col, int N, int E) {
    __shared__ int lcnt[NPB];    // counts, later fill cursors
    __shared__ int lscan[NPB];   // inclusive -> exclusive scan
    __shared__ int lcol[LCAP];
    int b = blockIdx.x, t = threadIdx.x;
    int lo = b << NPB_SHIFT, hi = min(N, lo + NPB), nn = hi - lo;
    int e0 = bstart[b], e1 = bstart[b + 1];
    lcnt[t] = 0; __syncthreads();
    for (int i = e0 + t; i < e1; i += 512)
        atomicAdd(&lcnt[(int)pairs[i].y - lo], 1);
    __syncthreads();
    int myc = (t < nn) ? lcnt[t] : 0;
    lscan[t] = myc; __syncthreads();
    for (int off = 1; off < 512; off <<= 1) {
        int u = (t >= off) ? lscan[t - off] : 0;
        __syncthreads();
        lscan[t] += u;
        __syncthreads();
    }
    if (t < nn) {
        rowptr[lo + t] = e0 + lscan[t] - myc;
        dinv[lo + t] = rsqrtf((float)(myc + 1));   // +1 self-loop
    }
    if (t == 0 && hi == N) rowptr[N] = E;
    __syncthreads();
    lscan[t] -= myc;          // exclusive (local col base per node)
    lcnt[t] = 0;              // reuse as fill cursors
    __syncthreads();
    for (int i = e0 + t; i < e1; i += 512) {
        uint2 p = pairs[i];
        int n = (int)p.y - lo;
        int slot = atomicAdd(&lcnt[n], 1);
        int idx = lscan[n] + slot;
        if (idx < LCAP) lcol[idx] = (int)p.x;
    }
    __syncthreads();
    int cnt = e1 - e0;
    for (int i = t; i < cnt; i += 512) col[e0 + i] = lcol[i];
}

// ---------------- GEMM: out[r][c] = dinv[r] * sum_k X[r][k] * W[k][c] ----------------

template<int D, int F, int THREADS, int RPB>
__global__ __launch_bounds__(THREADS) void k_gemm(
    const float* __restrict__ X, const float* __restrict__ W,
    const float* __restrict__ dinv, float* __restrict__ out, int N) {
    constexpr int CG = F / 4;           // col groups
    constexpr int XLD = D + 4;          // padded row stride
    __shared__ float Ws[D * F];
    __shared__ float Xs[RPB * XLD];
    int tid = threadIdx.x;
    int row0 = blockIdx.x * RPB;

    for (int i = tid; i < D * F / 4; i += THREADS)
        ((float4*)Ws)[i] = ((const float4*)W)[i];
    for (int i = tid; i < RPB * D / 4; i += THREADS) {
        int r = i / (D / 4), kk = i % (D / 4);
        int grow = row0 + r;
        float4 v = make_float4(0.f, 0.f, 0.f, 0.f);
        if (grow < N) v = *(const float4*)&X[(size_t)grow * D + kk * 4];
        *(float4*)&Xs[r * XLD + kk * 4] = v;
    }
    __syncthreads();

    int cg = tid % CG, rg = tid / CG;
    float acc[4][4] = {};
    const float* xb = &Xs[(rg * 4) * XLD];
    #pragma unroll 4
    for (int k = 0; k < D; ++k) {
        float4 w = *(float4*)&Ws[k * F + cg * 4];
        float x0 = xb[0 * XLD + k];
        float x1 = xb[1 * XLD + k];
        float x2 = xb[2 * XLD + k];
        float x3 = xb[3 * XLD + k];
        acc[0][0] += x0 * w.x; acc[0][1] += x0 * w.y; acc[0][2] += x0 * w.z; acc[0][3] += x0 * w.w;
        acc[1][0] += x1 * w.x; acc[1][1] += x1 * w.y; acc[1][2] += x1 * w.z; acc[1][3] += x1 * w.w;
        acc[2][0] += x2 * w.x; acc[2][1] += x2 * w.y; acc[2][2] += x2 * w.z; acc[2][3] += x2 * w.w;
        acc[3][0] += x3 * w.x; acc[3][1] += x3 * w.y; acc[3][2] += x3 * w.z; acc[3][3] += x3 * w.w;
    }
    #pragma unroll
    for (int i = 0; i < 4; i++) {
        int grow = row0 + rg * 4 + i;
        if (grow < N) {
            float dv = dinv[grow];
            float4 o = make_float4(acc[i][0] * dv, acc[i][1] * dv, acc[i][2] * dv, acc[i][3] * dv);
            *(float4*)&out[(size_t)grow * F + cg * 4] = o;
        }
    }
}

// ---------------- Aggregation: wave per node, lane = feature ----------------

__global__ __launch_bounds__(256) void k_agg1(
    const float* __restrict__ g1, const int* __restrict__ rowptr,
    const int* __restrict__ col, const float* __restrict__ dinv,
    const float* __restrict__ b1, float* __restrict__ out1, int N) {
    int wid = (int)((blockIdx.x * blockDim.x + threadIdx.x) >> 6);
    int lane = threadIdx.x & 63;
    if (wid >= N) return;
    int r0 = rowptr[wid], r1 = rowptr[wid + 1];
    float sum = g1[(size_t)wid * 64 + lane];   // self-loop term (g1 already has dinv[src])
    int e = r0;
    for (; e + 4 <= r1; e += 4) {
        int c0 = col[e], c1 = col[e + 1], c2 = col[e + 2], c3 = col[e + 3];
        float v0 = g1[(size_t)c0 * 64 + lane];
        float v1 = g1[(size_t)c1 * 64 + lane];
        float v2 = g1[(size_t)c2 * 64 + lane];
        float v3 = g1[(size_t)c3 * 64 + lane];
        sum += v0 + v1 + v2 + v3;
    }
    for (; e < r1; ++e) sum += g1[(size_t)col[e] * 64 + lane];
    out1[(size_t)wid * 64 + lane] = fmaxf(dinv[wid] * sum + b1[lane], 0.f);
}

__global__ __launch_bounds__(256) void k_agg2(
    const float* __restrict__ g2, const int* __restrict__ rowptr,
    const int* __restrict__ col, const float* __restrict__ dinv,
    const float* __restrict__ b2, float* __restrict__ out, int N) {
    int wid = (int)((blockIdx.x * blockDim.x + threadIdx.x) >> 6);
    int lane = threadIdx.x & 63;
    if (wid >= N) return;
    int cl = lane < 40 ? lane : 39;            // lanes >= 40 duplicate lane 39 (masked later)
    int r0 = rowptr[wid], r1 = rowptr[wid + 1];
    float sum = g2[(size_t)wid * 40 + cl];     // self-loop
    int e = r0;
    for (; e + 4 <= r1; e += 4) {
        int c0 = col[e], c1 = col[e + 1], c2 = col[e + 2], c3 = col[e + 3];
        float v0 = g2[(size_t)c0 * 40 + cl];
        float v1 = g2[(size_t)c1 * 40 + cl];
        float v2 = g2[(size_t)c2 * 40 + cl];
        float v3 = g2[(size_t)c3 * 40 + cl];
        sum += v0 + v1 + v2 + v3;
    }
    for (; e < r1; ++e) sum += g2[(size_t)col[e] * 40 + cl];
    float o = dinv[wid] * sum + b2[cl];
    // log-softmax over 40 classes (lanes >= 40 masked out of the reductions)
    float m = (lane < 40) ? o : -INFINITY;
    #pragma unroll
    for (int off = 32; off > 0; off >>= 1) m = fmaxf(m, __shfl_xor(m, off, 64));
    float p = (lane < 40) ? __expf(o - m) : 0.f;
    #pragma unroll
    for (int off = 32; off > 0; off >>= 1) p += __shfl_xor(p, off, 64);
    float l = __logf(p);
    if (lane < 40) out[(size_t)wid * 40 + lane] = o - m - l;
}

// ---------------- launch ----------------

extern "C" void kernel_launch(void* const* d_in, const int* in_sizes, int n_in,
                              void* d_out, int out_size, void* d_ws, size_t ws_size,
                              hipStream_t stream) {
    const float* x  = (const float*)d_in[0];
    const int*   ei = (const int*)d_in[1];      // [2, E] int32
    const float* W1 = (const float*)d_in[2];
    const float* b1 = (const float*)d_in[3];
    const float* W2 = (const float*)d_in[4];
    const float* b2 = (const float*)d_in[5];
    float* out = (float*)d_out;

    const int N = in_sizes[0] / 128;
    const int E = in_sizes[1] / 2;
    const int B = (N + NPB - 1) >> NPB_SHIFT;   // 196 buckets
    const int* src = ei;
    const int* dst = ei + E;

    char* w = (char*)d_ws;
    size_t off = 0;
    auto alloc = [&](size_t bytes) -> char* {
        char* p = w + off;
        off += (bytes + 255) & ~(size_t)255;
        return p;
    };
    int*   bcnt   = (int*)alloc((size_t)(B + 1) * 4);
    int*   bstart = (int*)alloc((size_t)(B + 1) * 4);
    int*   cursor = (int*)alloc((size_t)B * 4);
    int*   rowptr = (int*)alloc((size_t)(N + 1) * 4);
    float* dinv   = (float*)alloc((size_t)N * 4);
    int*   col    = (int*)alloc((size_t)E * 4);
    float* g1     = (float*)alloc((size_t)N * 64 * 4);
    float* out1   = (float*)alloc((size_t)N * 64 * 4);
    uint2* pairs  = (uint2*)g1;   // 12.8MB aliases g1 (dead until gemm1, after p2)
    float* g2     = g1;           // g1 dead after agg1; reuse for layer-2 pre-agg

    k_zeroB<<<1, 256, 0, stream>>>(bcnt, B);
    k_p1count<<<256, 256, 0, stream>>>(dst, E, B, bcnt);
    k_scanB<<<1, 256, 0, stream>>>(bcnt, B, E, bstart, cursor);
    int nch = (E + P1C - 1) / P1C;
    k_p1place<<<nch, 256, 0, stream>>>(src, dst, E, B, cursor, pairs);
    k_p2<<<B, 512, 0, stream>>>(pairs, bstart, rowptr, dinv, col, N, E);

    // layer 1: g1 = dinv * (x @ W1); agg + relu -> out1
    k_gemm<128, 64, 256, 64><<<(N + 63) / 64, 256, 0, stream>>>(x, W1, dinv, g1, N);
    k_agg1<<<(N + 3) / 4, 256, 0, stream>>>(g1, rowptr, col, dinv, b1, out1, N);

    // layer 2: g2 = dinv * (out1 @ W2); agg + bias + log_softmax -> out
    k_gemm<64, 40, 320, 128><<<(N + 127) / 128, 320, 0, stream>>>(out1, W2, dinv, g2, N);
    k_agg2<<<(N + 3) / 4, 256, 0, stream>>>(g2, rowptr, col, dinv, b2, out, N);
}

// Round 8
// 243.621 us; speedup vs baseline: 1.5120x; 1.0424x over previous
//
#include <hip/hip_runtime.h>
#include <hip/hip_bf16.h>
#include <math.h>

typedef long long i64;

// ================= CSR build: 2-phase radix partition by dst =================
#define NPB_SHIFT 9
#define NPB 512
#define LCAP 16384
#define P1C 4096

__global__ void k_zeroB(int* __restrict__ bcnt, int B) {
    int t = threadIdx.x;
    if (t <= B) bcnt[t] = 0;
}

__global__ __launch_bounds__(256) void k_p1count(
    const int* __restrict__ dst, int E, int B, int* __restrict__ bcnt) {
    __shared__ int lb[256];
    int t = threadIdx.x;
    lb[t] = 0; __syncthreads();
    int cpb = (E + gridDim.x - 1) / gridDim.x;
    int s0 = blockIdx.x * cpb, s1 = min(E, s0 + cpb);
    for (int i = s0 + t; i < s1; i += 256)
        atomicAdd(&lb[dst[i] >> NPB_SHIFT], 1);
    __syncthreads();
    if (t < B && lb[t]) atomicAdd(&bcnt[t], lb[t]);
}

__global__ void k_scanB(const int* __restrict__ bcnt, int B, int E,
                        int* __restrict__ bstart, int* __restrict__ cursor) {
    __shared__ int s[256];
    int t = threadIdx.x;
    int v = (t < B) ? bcnt[t] : 0;
    s[t] = v; __syncthreads();
    for (int off = 1; off < 256; off <<= 1) {
        int u = (t >= off) ? s[t - off] : 0;
        __syncthreads();
        s[t] += u;
        __syncthreads();
    }
    int excl = s[t] - v;
    if (t < B) { bstart[t] = excl; cursor[t] = excl; }
    if (t == 0) bstart[B] = E;
}

__global__ __launch_bounds__(256) void k_p1place(
    const int* __restrict__ src, const int* __restrict__ dst, int E, int B,
    int* __restrict__ cursor, uint2* __restrict__ pairs) {
    __shared__ int ls_s[P1C];
    __shared__ int ls_d[P1C];
    __shared__ int lb[256];
    __shared__ int lbase[256];
    int t = threadIdx.x;
    int s0 = blockIdx.x * P1C, s1 = min(E, s0 + P1C), n = s1 - s0;
    lb[t] = 0; __syncthreads();
    for (int i = t; i < n; i += 256) {
        int d = dst[s0 + i];
        ls_d[i] = d;
        ls_s[i] = src[s0 + i];
        atomicAdd(&lb[d >> NPB_SHIFT], 1);
    }
    __syncthreads();
    if (t < B && lb[t]) lbase[t] = atomicAdd(&cursor[t], lb[t]);
    __syncthreads();
    lb[t] = 0; __syncthreads();
    for (int i = t; i < n; i += 256) {
        int d = ls_d[i];
        int bkt = d >> NPB_SHIFT;
        int slot = atomicAdd(&lb[bkt], 1);
        pairs[lbase[bkt] + slot] = make_uint2((unsigned)ls_s[i], (unsigned)d);
    }
}

__global__ __launch_bounds__(512) void k_p2(
    const uint2* __restrict__ pairs, const int* __restrict__ bstart,
    int* __restrict__ rowptr, float* __restrict__ dinv,
    int* __restrict__ col, int N, int E) {
    __shared__ int lcnt[NPB];
    __shared__ int lscan[NPB];
    __shared__ int lcol[LCAP];
    int b = blockIdx.x, t = threadIdx.x;
    int lo = b << NPB_SHIFT, hi = min(N, lo + NPB), nn = hi - lo;
    int e0 = bstart[b], e1 = bstart[b + 1];
    lcnt[t] = 0; __syncthreads();
    for (int i = e0 + t; i < e1; i += 512)
        atomicAdd(&lcnt[(int)pairs[i].y - lo], 1);
    __syncthreads();
    int myc = (t < nn) ? lcnt[t] : 0;
    lscan[t] = myc; __syncthreads();
    for (int off = 1; off < 512; off <<= 1) {
        int u = (t >= off) ? lscan[t - off] : 0;
        __syncthreads();
        lscan[t] += u;
        __syncthreads();
    }
    if (t < nn) {
        rowptr[lo + t] = e0 + lscan[t] - myc;
        dinv[lo + t] = rsqrtf((float)(myc + 1));   // +1 self-loop
    }
    if (t == 0 && hi == N) rowptr[N] = E;
    __syncthreads();
    lscan[t] -= myc;
    lcnt[t] = 0;
    __syncthreads();
    for (int i = e0 + t; i < e1; i += 512) {
        uint2 p = pairs[i];
        int n = (int)p.y - lo;
        int slot = atomicAdd(&lcnt[n], 1);
        int idx = lscan[n] + slot;
        if (idx < LCAP) lcol[idx] = (int)p.x;
    }
    __syncthreads();
    int cnt = e1 - e0;
    for (int i = t; i < cnt; i += 512) col[e0 + i] = lcol[i];
}

// ------- GEMM: out[r][c] = bf16( dinv[r] * sum_k X[r][k]*W[k][c] ) -------
// bf16 output halves gather-array bytes for the downstream agg (R7: agg FETCH
// dominated; 164MB on g2 alone).

union BF4 { ushort4 u; __hip_bfloat16 h[4]; };

template<int D, int F, int THREADS, int RPB>
__global__ __launch_bounds__(THREADS) void k_gemm(
    const float* __restrict__ X, const float* __restrict__ W,
    const float* __restrict__ dinv, __hip_bfloat16* __restrict__ out, int N) {
    constexpr int CG = F / 4;
    constexpr int XLD = D + 4;
    __shared__ float Ws[D * F];
    __shared__ float Xs[RPB * XLD];
    int tid = threadIdx.x;
    int row0 = blockIdx.x * RPB;

    for (int i = tid; i < D * F / 4; i += THREADS)
        ((float4*)Ws)[i] = ((const float4*)W)[i];
    for (int i = tid; i < RPB * D / 4; i += THREADS) {
        int r = i / (D / 4), kk = i % (D / 4);
        int grow = row0 + r;
        float4 v = make_float4(0.f, 0.f, 0.f, 0.f);
        if (grow < N) v = *(const float4*)&X[(size_t)grow * D + kk * 4];
        *(float4*)&Xs[r * XLD + kk * 4] = v;
    }
    __syncthreads();

    int cg = tid % CG, rg = tid / CG;
    float acc[4][4] = {};
    const float* xb = &Xs[(rg * 4) * XLD];
    #pragma unroll 4
    for (int k = 0; k < D; ++k) {
        float4 w = *(float4*)&Ws[k * F + cg * 4];
        float x0 = xb[0 * XLD + k];
        float x1 = xb[1 * XLD + k];
        float x2 = xb[2 * XLD + k];
        float x3 = xb[3 * XLD + k];
        acc[0][0] += x0 * w.x; acc[0][1] += x0 * w.y; acc[0][2] += x0 * w.z; acc[0][3] += x0 * w.w;
        acc[1][0] += x1 * w.x; acc[1][1] += x1 * w.y; acc[1][2] += x1 * w.z; acc[1][3] += x1 * w.w;
        acc[2][0] += x2 * w.x; acc[2][1] += x2 * w.y; acc[2][2] += x2 * w.z; acc[2][3] += x2 * w.w;
        acc[3][0] += x3 * w.x; acc[3][1] += x3 * w.y; acc[3][2] += x3 * w.z; acc[3][3] += x3 * w.w;
    }
    #pragma unroll
    for (int i = 0; i < 4; i++) {
        int grow = row0 + rg * 4 + i;
        if (grow < N) {
            float dv = dinv[grow];
            BF4 o;
            o.h[0] = __float2bfloat16(acc[i][0] * dv);
            o.h[1] = __float2bfloat16(acc[i][1] * dv);
            o.h[2] = __float2bfloat16(acc[i][2] * dv);
            o.h[3] = __float2bfloat16(acc[i][3] * dv);
            *(ushort4*)&out[(size_t)grow * F + cg * 4] = o.u;
        }
    }
}

// ------------- Aggregation: wave per node, lane = feature (bf16 gather) -------------

__global__ __launch_bounds__(256) void k_agg1(
    const __hip_bfloat16* __restrict__ g1, const int* __restrict__ rowptr,
    const int* __restrict__ col, const float* __restrict__ dinv,
    const float* __restrict__ b1, float* __restrict__ out1, int N) {
    int wid = (int)((blockIdx.x * blockDim.x + threadIdx.x) >> 6);
    int lane = threadIdx.x & 63;
    if (wid >= N) return;
    int r0 = rowptr[wid], r1 = rowptr[wid + 1];
    float sum = __bfloat162float(g1[(size_t)wid * 64 + lane]);   // self-loop
    int e = r0;
    for (; e + 4 <= r1; e += 4) {
        int c0 = col[e], c1 = col[e + 1], c2 = col[e + 2], c3 = col[e + 3];
        float v0 = __bfloat162float(g1[(size_t)c0 * 64 + lane]);
        float v1 = __bfloat162float(g1[(size_t)c1 * 64 + lane]);
        float v2 = __bfloat162float(g1[(size_t)c2 * 64 + lane]);
        float v3 = __bfloat162float(g1[(size_t)c3 * 64 + lane]);
        sum += v0 + v1 + v2 + v3;
    }
    for (; e < r1; ++e) sum += __bfloat162float(g1[(size_t)col[e] * 64 + lane]);
    out1[(size_t)wid * 64 + lane] = fmaxf(dinv[wid] * sum + b1[lane], 0.f);
}

__global__ __launch_bounds__(256) void k_agg2(
    const __hip_bfloat16* __restrict__ g2, const int* __restrict__ rowptr,
    const int* __restrict__ col, const float* __restrict__ dinv,
    const float* __restrict__ b2, float* __restrict__ out, int N) {
    int wid = (int)((blockIdx.x * blockDim.x + threadIdx.x) >> 6);
    int lane = threadIdx.x & 63;
    if (wid >= N) return;
    int cl = lane < 40 ? lane : 39;
    int r0 = rowptr[wid], r1 = rowptr[wid + 1];
    float sum = __bfloat162float(g2[(size_t)wid * 40 + cl]);   // self-loop
    int e = r0;
    for (; e + 4 <= r1; e += 4) {
        int c0 = col[e], c1 = col[e + 1], c2 = col[e + 2], c3 = col[e + 3];
        float v0 = __bfloat162float(g2[(size_t)c0 * 40 + cl]);
        float v1 = __bfloat162float(g2[(size_t)c1 * 40 + cl]);
        float v2 = __bfloat162float(g2[(size_t)c2 * 40 + cl]);
        float v3 = __bfloat162float(g2[(size_t)c3 * 40 + cl]);
        sum += v0 + v1 + v2 + v3;
    }
    for (; e < r1; ++e) sum += __bfloat162float(g2[(size_t)col[e] * 40 + cl]);
    float o = dinv[wid] * sum + b2[cl];
    float m = (lane < 40) ? o : -INFINITY;
    #pragma unroll
    for (int off = 32; off > 0; off >>= 1) m = fmaxf(m, __shfl_xor(m, off, 64));
    float p = (lane < 40) ? __expf(o - m) : 0.f;
    #pragma unroll
    for (int off = 32; off > 0; off >>= 1) p += __shfl_xor(p, off, 64);
    float l = __logf(p);
    if (lane < 40) out[(size_t)wid * 40 + lane] = o - m - l;
}

// ---------------- launch ----------------

extern "C" void kernel_launch(void* const* d_in, const int* in_sizes, int n_in,
                              void* d_out, int out_size, void* d_ws, size_t ws_size,
                              hipStream_t stream) {
    const float* x  = (const float*)d_in[0];
    const int*   ei = (const int*)d_in[1];
    const float* W1 = (const float*)d_in[2];
    const float* b1 = (const float*)d_in[3];
    const float* W2 = (const float*)d_in[4];
    const float* b2 = (const float*)d_in[5];
    float* out = (float*)d_out;

    const int N = in_sizes[0] / 128;
    const int E = in_sizes[1] / 2;
    const int B = (N + NPB - 1) >> NPB_SHIFT;
    const int* src = ei;
    const int* dst = ei + E;

    char* w = (char*)d_ws;
    size_t off = 0;
    auto alloc = [&](size_t bytes) -> char* {
        char* p = w + off;
        off += (bytes + 255) & ~(size_t)255;
        return p;
    };
    int*   bcnt   = (int*)alloc((size_t)(B + 1) * 4);
    int*   bstart = (int*)alloc((size_t)(B + 1) * 4);
    int*   cursor = (int*)alloc((size_t)B * 4);
    int*   rowptr = (int*)alloc((size_t)(N + 1) * 4);
    float* dinv   = (float*)alloc((size_t)N * 4);
    int*   col    = (int*)alloc((size_t)E * 4);
    // shared buffer: pairs (E*8B) before GEMMs; g1 bf16 (N*64*2B) / g2 bf16 after
    size_t shbytes = (size_t)E * 8 > (size_t)N * 64 * 2 ? (size_t)E * 8 : (size_t)N * 64 * 2;
    char*  sh     = alloc(shbytes);
    float* out1   = (float*)alloc((size_t)N * 64 * 4);
    uint2* pairs  = (uint2*)sh;
    __hip_bfloat16* g1 = (__hip_bfloat16*)sh;   // pairs dead after k_p2
    __hip_bfloat16* g2 = (__hip_bfloat16*)sh;   // g1 dead after agg1

    k_zeroB<<<1, 256, 0, stream>>>(bcnt, B);
    k_p1count<<<256, 256, 0, stream>>>(dst, E, B, bcnt);
    k_scanB<<<1, 256, 0, stream>>>(bcnt, B, E, bstart, cursor);
    int nch = (E + P1C - 1) / P1C;
    k_p1place<<<nch, 256, 0, stream>>>(src, dst, E, B, cursor, pairs);
    k_p2<<<B, 512, 0, stream>>>(pairs, bstart, rowptr, dinv, col, N, E);

    // layer 1: g1 = bf16(dinv * (x @ W1)); agg + relu -> out1 (fp32)
    k_gemm<128, 64, 256, 64><<<(N + 63) / 64, 256, 0, stream>>>(x, W1, dinv, g1, N);
    k_agg1<<<(N + 3) / 4, 256, 0, stream>>>(g1, rowptr, col, dinv, b1, out1, N);

    // layer 2: g2 = bf16(dinv * (out1 @ W2)); agg + bias + log_softmax -> out
    k_gemm<64, 40, 320, 128><<<(N + 127) / 128, 320, 0, stream>>>(out1, W2, dinv, g2, N);
    k_agg2<<<(N + 3) / 4, 256, 0, stream>>>(g2, rowptr, col, dinv, b2, out, N);
}

// Round 9
// 223.931 us; speedup vs baseline: 1.6449x; 1.0879x over previous
//
#include <hip/hip_runtime.h>
#include <hip/hip_bf16.h>
#include <math.h>

typedef long long i64;

// ================= CSR build: 2-phase radix partition by dst =================
#define NPB_SHIFT 9
#define NPB 512
#define LCAP 16384
#define P1C 4096

__global__ void k_zeroB(int* __restrict__ bcnt, int B) {
    int t = threadIdx.x;
    if (t <= B) bcnt[t] = 0;
}

__global__ __launch_bounds__(256) void k_p1count(
    const int* __restrict__ dst, int E, int B, int* __restrict__ bcnt) {
    __shared__ int lb[256];
    int t = threadIdx.x;
    lb[t] = 0; __syncthreads();
    int cpb = (E + gridDim.x - 1) / gridDim.x;
    int s0 = blockIdx.x * cpb, s1 = min(E, s0 + cpb);
    for (int i = s0 + t; i < s1; i += 256)
        atomicAdd(&lb[dst[i] >> NPB_SHIFT], 1);
    __syncthreads();
    if (t < B && lb[t]) atomicAdd(&bcnt[t], lb[t]);
}

__global__ void k_scanB(const int* __restrict__ bcnt, int B, int E,
                        int* __restrict__ bstart, int* __restrict__ cursor) {
    __shared__ int s[256];
    int t = threadIdx.x;
    int v = (t < B) ? bcnt[t] : 0;
    s[t] = v; __syncthreads();
    for (int off = 1; off < 256; off <<= 1) {
        int u = (t >= off) ? s[t - off] : 0;
        __syncthreads();
        s[t] += u;
        __syncthreads();
    }
    int excl = s[t] - v;
    if (t < B) { bstart[t] = excl; cursor[t] = excl; }
    if (t == 0) bstart[B] = E;
}

__global__ __launch_bounds__(256) void k_p1place(
    const int* __restrict__ src, const int* __restrict__ dst, int E, int B,
    int* __restrict__ cursor, uint2* __restrict__ pairs) {
    __shared__ int ls_s[P1C];
    __shared__ int ls_d[P1C];
    __shared__ int lb[256];
    __shared__ int lbase[256];
    int t = threadIdx.x;
    int s0 = blockIdx.x * P1C, s1 = min(E, s0 + P1C), n = s1 - s0;
    lb[t] = 0; __syncthreads();
    for (int i = t; i < n; i += 256) {
        int d = dst[s0 + i];
        ls_d[i] = d;
        ls_s[i] = src[s0 + i];
        atomicAdd(&lb[d >> NPB_SHIFT], 1);
    }
    __syncthreads();
    if (t < B && lb[t]) lbase[t] = atomicAdd(&cursor[t], lb[t]);
    __syncthreads();
    lb[t] = 0; __syncthreads();
    for (int i = t; i < n; i += 256) {
        int d = ls_d[i];
        int bkt = d >> NPB_SHIFT;
        int slot = atomicAdd(&lb[bkt], 1);
        pairs[lbase[bkt] + slot] = make_uint2((unsigned)ls_s[i], (unsigned)d);
    }
}

__global__ __launch_bounds__(512) void k_p2(
    const uint2* __restrict__ pairs, const int* __restrict__ bstart,
    int* __restrict__ rowptr, float* __restrict__ dinv,
    int* __restrict__ col, int N, int E) {
    __shared__ int lcnt[NPB];
    __shared__ int lscan[NPB];
    __shared__ int lcol[LCAP];
    int b = blockIdx.x, t = threadIdx.x;
    int lo = b << NPB_SHIFT, hi = min(N, lo + NPB), nn = hi - lo;
    int e0 = bstart[b], e1 = bstart[b + 1];
    lcnt[t] = 0; __syncthreads();
    for (int i = e0 + t; i < e1; i += 512)
        atomicAdd(&lcnt[(int)pairs[i].y - lo], 1);
    __syncthreads();
    int myc = (t < nn) ? lcnt[t] : 0;
    lscan[t] = myc; __syncthreads();
    for (int off = 1; off < 512; off <<= 1) {
        int u = (t >= off) ? lscan[t - off] : 0;
        __syncthreads();
        lscan[t] += u;
        __syncthreads();
    }
    if (t < nn) {
        rowptr[lo + t] = e0 + lscan[t] - myc;
        dinv[lo + t] = rsqrtf((float)(myc + 1));   // +1 self-loop
    }
    if (t == 0 && hi == N) rowptr[N] = E;
    __syncthreads();
    lscan[t] -= myc;
    lcnt[t] = 0;
    __syncthreads();
    for (int i = e0 + t; i < e1; i += 512) {
        uint2 p = pairs[i];
        int n = (int)p.y - lo;
        int slot = atomicAdd(&lcnt[n], 1);
        int idx = lscan[n] + slot;
        if (idx < LCAP) lcol[idx] = (int)p.x;
    }
    __syncthreads();
    int cnt = e1 - e0;
    for (int i = t; i < cnt; i += 512) col[e0 + i] = lcol[i];
}

// ------- GEMM: out[r][c] = bf16( dinv[r] * sum_k X[r][k]*W[k][c] ) -------

union BF4 { ushort4 u; __hip_bfloat16 h[4]; };

template<int D, int F, int THREADS, int RPB>
__global__ __launch_bounds__(THREADS) void k_gemm(
    const float* __restrict__ X, const float* __restrict__ W,
    const float* __restrict__ dinv, __hip_bfloat16* __restrict__ out, int N) {
    constexpr int CG = F / 4;
    constexpr int XLD = D + 4;
    __shared__ float Ws[D * F];
    __shared__ float Xs[RPB * XLD];
    int tid = threadIdx.x;
    int row0 = blockIdx.x * RPB;

    for (int i = tid; i < D * F / 4; i += THREADS)
        ((float4*)Ws)[i] = ((const float4*)W)[i];
    for (int i = tid; i < RPB * D / 4; i += THREADS) {
        int r = i / (D / 4), kk = i % (D / 4);
        int grow = row0 + r;
        float4 v = make_float4(0.f, 0.f, 0.f, 0.f);
        if (grow < N) v = *(const float4*)&X[(size_t)grow * D + kk * 4];
        *(float4*)&Xs[r * XLD + kk * 4] = v;
    }
    __syncthreads();

    int cg = tid % CG, rg = tid / CG;
    float acc[4][4] = {};
    const float* xb = &Xs[(rg * 4) * XLD];
    #pragma unroll 4
    for (int k = 0; k < D; ++k) {
        float4 w = *(float4*)&Ws[k * F + cg * 4];
        float x0 = xb[0 * XLD + k];
        float x1 = xb[1 * XLD + k];
        float x2 = xb[2 * XLD + k];
        float x3 = xb[3 * XLD + k];
        acc[0][0] += x0 * w.x; acc[0][1] += x0 * w.y; acc[0][2] += x0 * w.z; acc[0][3] += x0 * w.w;
        acc[1][0] += x1 * w.x; acc[1][1] += x1 * w.y; acc[1][2] += x1 * w.z; acc[1][3] += x1 * w.w;
        acc[2][0] += x2 * w.x; acc[2][1] += x2 * w.y; acc[2][2] += x2 * w.z; acc[2][3] += x2 * w.w;
        acc[3][0] += x3 * w.x; acc[3][1] += x3 * w.y; acc[3][2] += x3 * w.z; acc[3][3] += x3 * w.w;
    }
    #pragma unroll
    for (int i = 0; i < 4; i++) {
        int grow = row0 + rg * 4 + i;
        if (grow < N) {
            float dv = dinv[grow];
            BF4 o;
            o.h[0] = __float2bfloat16(acc[i][0] * dv);
            o.h[1] = __float2bfloat16(acc[i][1] * dv);
            o.h[2] = __float2bfloat16(acc[i][2] * dv);
            o.h[3] = __float2bfloat16(acc[i][3] * dv);
            *(ushort4*)&out[(size_t)grow * F + cg * 4] = o.u;
        }
    }
}

// ------------- Aggregation: wave per node, lane = feature (bf16 gather) -------------
// R8: latency-bound (FETCH halved, dur flat). Fix: 16 independent gathers in
// flight per batch (4x deeper MLP), tree-summed.

__global__ __launch_bounds__(256) void k_agg1(
    const __hip_bfloat16* __restrict__ g1, const int* __restrict__ rowptr,
    const int* __restrict__ col, const float* __restrict__ dinv,
    const float* __restrict__ b1, float* __restrict__ out1, int N) {
    int wid = (int)((blockIdx.x * blockDim.x + threadIdx.x) >> 6);
    int lane = threadIdx.x & 63;
    if (wid >= N) return;
    int r0 = rowptr[wid], r1 = rowptr[wid + 1];
    float sum = __bfloat162float(g1[(size_t)wid * 64 + lane]);   // self-loop
    int e = r0;
    for (; e + 16 <= r1; e += 16) {
        int c[16];
        #pragma unroll
        for (int j = 0; j < 16; j++) c[j] = col[e + j];
        float v[16];
        #pragma unroll
        for (int j = 0; j < 16; j++)
            v[j] = __bfloat162float(g1[(size_t)c[j] * 64 + lane]);
        #pragma unroll
        for (int s = 1; s < 16; s <<= 1)
            #pragma unroll
            for (int j = 0; j < 16; j += 2 * s) v[j] += v[j + s];
        sum += v[0];
    }
    for (; e + 4 <= r1; e += 4) {
        int c0 = col[e], c1 = col[e + 1], c2 = col[e + 2], c3 = col[e + 3];
        float v0 = __bfloat162float(g1[(size_t)c0 * 64 + lane]);
        float v1 = __bfloat162float(g1[(size_t)c1 * 64 + lane]);
        float v2 = __bfloat162float(g1[(size_t)c2 * 64 + lane]);
        float v3 = __bfloat162float(g1[(size_t)c3 * 64 + lane]);
        sum += (v0 + v1) + (v2 + v3);
    }
    for (; e < r1; ++e) sum += __bfloat162float(g1[(size_t)col[e] * 64 + lane]);
    out1[(size_t)wid * 64 + lane] = fmaxf(dinv[wid] * sum + b1[lane], 0.f);
}

__global__ __launch_bounds__(256) void k_agg2(
    const __hip_bfloat16* __restrict__ g2, const int* __restrict__ rowptr,
    const int* __restrict__ col, const float* __restrict__ dinv,
    const float* __restrict__ b2, float* __restrict__ out, int N) {
    int wid = (int)((blockIdx.x * blockDim.x + threadIdx.x) >> 6);
    int lane = threadIdx.x & 63;
    if (wid >= N) return;
    int cl = lane < 40 ? lane : 39;
    int r0 = rowptr[wid], r1 = rowptr[wid + 1];
    float sum = __bfloat162float(g2[(size_t)wid * 40 + cl]);   // self-loop
    int e = r0;
    for (; e + 16 <= r1; e += 16) {
        int c[16];
        #pragma unroll
        for (int j = 0; j < 16; j++) c[j] = col[e + j];
        float v[16];
        #pragma unroll
        for (int j = 0; j < 16; j++)
            v[j] = __bfloat162float(g2[(size_t)c[j] * 40 + cl]);
        #pragma unroll
        for (int s = 1; s < 16; s <<= 1)
            #pragma unroll
            for (int j = 0; j < 16; j += 2 * s) v[j] += v[j + s];
        sum += v[0];
    }
    for (; e + 4 <= r1; e += 4) {
        int c0 = col[e], c1 = col[e + 1], c2 = col[e + 2], c3 = col[e + 3];
        float v0 = __bfloat162float(g2[(size_t)c0 * 40 + cl]);
        float v1 = __bfloat162float(g2[(size_t)c1 * 40 + cl]);
        float v2 = __bfloat162float(g2[(size_t)c2 * 40 + cl]);
        float v3 = __bfloat162float(g2[(size_t)c3 * 40 + cl]);
        sum += (v0 + v1) + (v2 + v3);
    }
    for (; e < r1; ++e) sum += __bfloat162float(g2[(size_t)col[e] * 40 + cl]);
    float o = dinv[wid] * sum + b2[cl];
    float m = (lane < 40) ? o : -INFINITY;
    #pragma unroll
    for (int off = 32; off > 0; off >>= 1) m = fmaxf(m, __shfl_xor(m, off, 64));
    float p = (lane < 40) ? __expf(o - m) : 0.f;
    #pragma unroll
    for (int off = 32; off > 0; off >>= 1) p += __shfl_xor(p, off, 64);
    float l = __logf(p);
    if (lane < 40) out[(size_t)wid * 40 + lane] = o - m - l;
}

// ---------------- launch ----------------

extern "C" void kernel_launch(void* const* d_in, const int* in_sizes, int n_in,
                              void* d_out, int out_size, void* d_ws, size_t ws_size,
                              hipStream_t stream) {
    const float* x  = (const float*)d_in[0];
    const int*   ei = (const int*)d_in[1];
    const float* W1 = (const float*)d_in[2];
    const float* b1 = (const float*)d_in[3];
    const float* W2 = (const float*)d_in[4];
    const float* b2 = (const float*)d_in[5];
    float* out = (float*)d_out;

    const int N = in_sizes[0] / 128;
    const int E = in_sizes[1] / 2;
    const int B = (N + NPB - 1) >> NPB_SHIFT;
    const int* src = ei;
    const int* dst = ei + E;

    char* w = (char*)d_ws;
    size_t off = 0;
    auto alloc = [&](size_t bytes) -> char* {
        char* p = w + off;
        off += (bytes + 255) & ~(size_t)255;
        return p;
    };
    int*   bcnt   = (int*)alloc((size_t)(B + 1) * 4);
    int*   bstart = (int*)alloc((size_t)(B + 1) * 4);
    int*   cursor = (int*)alloc((size_t)B * 4);
    int*   rowptr = (int*)alloc((size_t)(N + 1) * 4);
    float* dinv   = (float*)alloc((size_t)N * 4);
    int*   col    = (int*)alloc((size_t)E * 4);
    size_t shbytes = (size_t)E * 8 > (size_t)N * 64 * 2 ? (size_t)E * 8 : (size_t)N * 64 * 2;
    char*  sh     = alloc(shbytes);
    float* out1   = (float*)alloc((size_t)N * 64 * 4);
    uint2* pairs  = (uint2*)sh;
    __hip_bfloat16* g1 = (__hip_bfloat16*)sh;   // pairs dead after k_p2
    __hip_bfloat16* g2 = (__hip_bfloat16*)sh;   // g1 dead after agg1

    k_zeroB<<<1, 256, 0, stream>>>(bcnt, B);
    k_p1count<<<256, 256, 0, stream>>>(dst, E, B, bcnt);
    k_scanB<<<1, 256, 0, stream>>>(bcnt, B, E, bstart, cursor);
    int nch = (E + P1C - 1) / P1C;
    k_p1place<<<nch, 256, 0, stream>>>(src, dst, E, B, cursor, pairs);
    k_p2<<<B, 512, 0, stream>>>(pairs, bstart, rowptr, dinv, col, N, E);

    // layer 1: g1 = bf16(dinv * (x @ W1)); agg + relu -> out1 (fp32)
    k_gemm<128, 64, 256, 64><<<(N + 63) / 64, 256, 0, stream>>>(x, W1, dinv, g1, N);
    k_agg1<<<(N + 3) / 4, 256, 0, stream>>>(g1, rowptr, col, dinv, b1, out1, N);

    // layer 2: g2 = bf16(dinv * (out1 @ W2)); agg + bias + log_softmax -> out
    k_gemm<64, 40, 320, 128><<<(N + 127) / 128, 320, 0, stream>>>(out1, W2, dinv, g2, N);
    k_agg2<<<(N + 3) / 4, 256, 0, stream>>>(g2, rowptr, col, dinv, b2, out, N);
}